// Round 5
// baseline (103.919 us; speedup 1.0000x reference)
//
#include <hip/hip_runtime.h>
#include <math.h>

#define TT 2048
#define CE 32

__device__ __forceinline__ float clip100(float v) {
    return fminf(fmaxf(v, -100.f), 100.f);
}

__device__ __forceinline__ float4 shfl_xor4(float4 v, int m) {
    float4 r;
    r.x = __shfl_xor(v.x, m, 64);
    r.y = __shfl_xor(v.y, m, 64);
    r.z = __shfl_xor(v.z, m, 64);
    r.w = __shfl_xor(v.w, m, 64);
    return r;
}

// ---------------------------------------------------------------------------
// Single fused kernel. 512 blocks x 256 threads; block = 16 tokens of batch b.
// tid = tl*16 + h*2 + s (tl token 0..15, h head 0..7, s half).
// Producer side: each block writes the 4-row-per-phase partial sums of its own
// x-tile to ws, fences, bumps cnt[b]. Consumer side (same blocks): after the
// independent q/rxtx/softmax work, spin-acquire on cnt[b], reduce the 128 tile
// partials (fixed order -> deterministic), build Z, emit output.
// Co-residency: 512 blocks, >=4 blocks/CU by LDS+VGPR -> spin cannot deadlock.
// ---------------------------------------------------------------------------
__global__ __launch_bounds__(256, 4) void k_fused(const float* __restrict__ x,
        const float* __restrict__ Wq, const float* __restrict__ bq,
        const float* __restrict__ Wv, const float* __restrict__ bv,
        const float* __restrict__ Wp, const float* __restrict__ bp,
        unsigned int* __restrict__ cnt, float* __restrict__ partial,
        float* __restrict__ out) {
    int blk = blockIdx.x;
    int b   = blk >> 7;                    // 128 blocks (tiles) per batch
    int tb  = blk & 127;                   // tile index within batch
    int t0  = tb * 16;
    int tid = threadIdx.x;
    int tl  = tid >> 4;                    // 0..15
    int h   = (tid >> 1) & 7;              // 0..7
    int s   = tid & 1;                     // 0..1

    __shared__ float xs[16][33];
    __shared__ float wqs[32][33];
    __shared__ float wvs[32][33];
    __shared__ float wps[32][33];
    __shared__ float pbuf[16][36];
    __shared__ float Zl[32][36];
    __shared__ float xavg[4][33];
    __shared__ float bqs[32], bvs[32], bps[32];

    // ---- stage: weights, x tile, biases ----
    {
        int rr = tid >> 3, cq = tid & 7;
        *reinterpret_cast<float4*>(&wqs[rr][cq * 4]) =
            *reinterpret_cast<const float4*>(Wq + rr * 32 + cq * 4);
        *reinterpret_cast<float4*>(&wvs[rr][cq * 4]) =
            *reinterpret_cast<const float4*>(Wv + rr * 32 + cq * 4);
        *reinterpret_cast<float4*>(&wps[rr][cq * 4]) =
            *reinterpret_cast<const float4*>(Wp + rr * 32 + cq * 4);
        if (tid < 128) {
            int r2 = tid >> 3, q2 = tid & 7;
            *reinterpret_cast<float4*>(&xs[r2][q2 * 4]) =
                *reinterpret_cast<const float4*>(x + ((size_t)b * TT + t0 + r2) * CE + q2 * 4);
        } else {
            int u = tid - 128;
            if (u < 32)      bqs[u] = bq[u];
            else if (u < 64) bvs[u - 32] = bv[u - 32];
            else if (u < 96) bps[u - 64] = bp[u - 64];
        }
    }
    __syncthreads();

    // ---- producer: tile partial sums (phase c, col e) -> ws, flag cnt[b] ----
    if (tid < 128) {
        int c = tid >> 5, e = tid & 31;
        float val = xs[c][e] + xs[4 + c][e] + xs[8 + c][e] + xs[12 + c][e];
        partial[((size_t)(b * 128 + tb) << 7) + tid] = val;
        __threadfence();                       // device-scope release
        atomicAdd(&cnt[b], 1u);                // coalesced per-wave
    }

    // ---- phase A: q half-dot (e-range s*16..), combine via shfl ----
    float4 myq;
    {
        float a0 = 0.f, a1 = 0.f, a2 = 0.f, a3 = 0.f;
#pragma unroll
        for (int e4 = 0; e4 < 4; ++e4) {
            int e = s * 16 + e4 * 4;
            float4 xv = *reinterpret_cast<const float4*>(&xs[tl][e]);
            float4 w0 = *reinterpret_cast<const float4*>(&wqs[4 * h + 0][e]);
            float4 w1 = *reinterpret_cast<const float4*>(&wqs[4 * h + 1][e]);
            float4 w2 = *reinterpret_cast<const float4*>(&wqs[4 * h + 2][e]);
            float4 w3 = *reinterpret_cast<const float4*>(&wqs[4 * h + 3][e]);
            a0 += xv.x * w0.x + xv.y * w0.y + xv.z * w0.z + xv.w * w0.w;
            a1 += xv.x * w1.x + xv.y * w1.y + xv.z * w1.z + xv.w * w1.w;
            a2 += xv.x * w2.x + xv.y * w2.y + xv.z * w2.z + xv.w * w2.w;
            a3 += xv.x * w3.x + xv.y * w3.y + xv.z * w3.z + xv.w * w3.w;
        }
        myq.x = clip100(bqs[4 * h + 0] + a0 + __shfl_xor(a0, 1, 64));
        myq.y = clip100(bqs[4 * h + 1] + a1 + __shfl_xor(a1, 1, 64));
        myq.z = clip100(bqs[4 * h + 2] + a2 + __shfl_xor(a2, 1, 64));
        myq.w = clip100(bqs[4 * h + 3] + a3 + __shfl_xor(a3, 1, 64));
    }

    // ---- phase B1: in-wave q-block exchange + rxtx + softmax ----
    {
        int r = tl & 3;
        float4 q16 = shfl_xor4(myq, 16);
        float4 q32 = shfl_xor4(myq, 32);
        float4 q48 = shfl_xor4(myq, 48);
        float4 R0 = (r == 0) ? myq : (r == 1) ? q16 : (r == 2) ? q32 : q48;
        float4 R1 = (r == 1) ? myq : (r == 0) ? q16 : (r == 3) ? q32 : q48;
        float4 R2 = (r == 2) ? myq : (r == 3) ? q16 : (r == 0) ? q32 : q48;
        float4 R3 = (r == 3) ? myq : (r == 2) ? q16 : (r == 1) ? q32 : q48;

        float X1 = R0.x, X2 = R0.y, X3 = R0.z, X4 = R0.w;
        float X5 = R1.x, X6 = R1.y, X7 = R1.z, X8 = R1.w;
        float X9 = R2.x, X10 = R2.y, X11 = R2.z, X12 = R2.w;
        float X13 = R3.x, X14 = R3.y, X15 = R3.z, X16 = R3.w;

        float m1  = (-X2 + X3 - X4 + X8) * (X8 + X11);
        float m2  = (X1 - X5 - X6 + X7) * (X15 + X5);
        float m3  = (-X2 + X12) * (-X10 + X16 + X12);
        float m4  = (X9 - X6) * (X13 + X9 - X14);
        float m5  = (X2 + X11) * (-X6 + X15 - X7);
        float m6  = (X6 + X11) * (X6 + X7 - X11);
        float m7  = X11 * (X6 + X7);
        float m8  = X2 * (-X14 - X10 + X6 - X15 + X7 + X16 + X12);
        float m9  = X6 * (X13 + X9 - X14 - X10 + X6 + X7 - X11);
        float m10 = (X2 - X3 + X7 + X11 + X4 - X8) * X11;
        float m11 = (X5 + X6 - X7) * X5;
        float m12 = (X2 - X3 + X4) * X8;
        float m13 = (-X1 + X5 + X6 + X3 - X7 + X11) * X15;
        float m14 = (-X1 + X5 + X6) * (X13 + X9 + X15);
        float m15 = (X2 + X4 - X8) * (X11 + X16 + X12);
        float m16 = (X1 - X8) * (X9 - X16);
        float m17 = X12 * (X10 - X12);
        float m18 = X9 * (X13 - X14);
        float m19 = (-X2 + X3) * (-X15 + X7 + X8);
        float m20 = (X5 + X9 - X8) * X9;
        float m21 = X8 * (X9 - X8 + X12);
        float m22 = (-X6 + X7) * (X5 + X7 - X11);
        float m23 = X1 * (X13 - X5 + X16);
        float m24 = (-X1 + X4 + X12) * X16;
        float m25 = (X9 + X2 + X10) * X14;
        float m26 = (X6 + X10 + X12) * X10;
        float z1 = m7 - m11 - m12;
        float z2 = m1 + m12 + m21;
        float z3 = m3 + m17 - m24;
        float z4 = m2 + m11 + m23;
        float z5 = m5 + m7 + m8;
        float z6 = m4 - m18 - m20;
        float z7 = m6 - m7 - m9;
        float z8 = m17 + m18;
        float c01 = m2 - m5 - z1 + m13 + m19;
        float c02 = z2 + z3 + m15 + m16;
        float c03 = z4 - z3 - z5 - m13;
        float c11 = m1 + m6 - z1 + m10 + m22;
        float c12 = z2 - z6 + z7 + m10;
        float c13 = z4 + z6 + m14 + m16;
        float c22 = m4 - z7 - z8 + m26;
        float c23 = m3 + z5 + z8 + m25;

        float g0, g1, g2, g3;
        if (r == 0)      { g0 = 0.f; g1 = c01; g2 = c02; g3 = c03; }
        else if (r == 1) { g0 = c01; g1 = c11; g2 = c12; g3 = c13; }
        else if (r == 2) { g0 = c02; g1 = c12; g2 = c22; g3 = c23; }
        else             { g0 = c03; g1 = c13; g2 = c23; g3 = 0.f; }
        g0 = clip100(g0) * 0.5f; g1 = clip100(g1) * 0.5f;
        g2 = clip100(g2) * 0.5f; g3 = clip100(g3) * 0.5f;

        float mx = fmaxf(fmaxf(g0, g1), fmaxf(g2, g3));
        float p0 = __expf(g0 - mx), p1 = __expf(g1 - mx);
        float p2 = __expf(g2 - mx), p3 = __expf(g3 - mx);
        float inv = 1.f / (p0 + p1 + p2 + p3);
        if (s == 0) {
            float4 pv; pv.x = p0 * inv; pv.y = p1 * inv;
            pv.z = p2 * inv; pv.w = p3 * inv;
            *reinterpret_cast<float4*>(&pbuf[tl][4 * h]) = pv;
        }
    }

    // ---- consumer: spin-acquire on cnt[b], reduce 128 tile partials ----
    if (tid < 128) {
        while (__hip_atomic_load(&cnt[b], __ATOMIC_ACQUIRE,
                                 __HIP_MEMORY_SCOPE_AGENT) < 16384u)
            __builtin_amdgcn_s_sleep(1);
        const float* pbase = partial + ((size_t)b << 14) + tid;
        float sm = 0.f;
#pragma unroll 8
        for (int t2 = 0; t2 < 128; ++t2)
            sm += pbase[t2 << 7];
        xavg[tid >> 5][tid & 31] = sm * (1.f / 512.f);
    }
    __syncthreads();

    // ---- phase B2: Z[k][4oq..] (k = tid>>3, oq = tid&7) ----
    {
        int k  = tid >> 3;
        int oq = tid & 7;
        int h2 = k >> 2, c2 = k & 3;
        float vv0 = bvs[4 * h2 + 0], vv1 = bvs[4 * h2 + 1];
        float vv2 = bvs[4 * h2 + 2], vv3 = bvs[4 * h2 + 3];
#pragma unroll
        for (int e4 = 0; e4 < 8; ++e4) {
            float xa0 = xavg[c2][e4 * 4 + 0];
            float xa1 = xavg[c2][e4 * 4 + 1];
            float xa2 = xavg[c2][e4 * 4 + 2];
            float xa3 = xavg[c2][e4 * 4 + 3];
            float4 w0 = *reinterpret_cast<const float4*>(&wvs[4 * h2 + 0][e4 * 4]);
            float4 w1 = *reinterpret_cast<const float4*>(&wvs[4 * h2 + 1][e4 * 4]);
            float4 w2 = *reinterpret_cast<const float4*>(&wvs[4 * h2 + 2][e4 * 4]);
            float4 w3 = *reinterpret_cast<const float4*>(&wvs[4 * h2 + 3][e4 * 4]);
            vv0 += xa0 * w0.x + xa1 * w0.y + xa2 * w0.z + xa3 * w0.w;
            vv1 += xa0 * w1.x + xa1 * w1.y + xa2 * w1.z + xa3 * w1.w;
            vv2 += xa0 * w2.x + xa1 * w2.y + xa2 * w2.z + xa3 * w2.w;
            vv3 += xa0 * w3.x + xa1 * w3.y + xa2 * w3.z + xa3 * w3.w;
        }
        float4 zv;
#pragma unroll
        for (int dd = 0; dd < 4; ++dd) {
            float4 wp = *reinterpret_cast<const float4*>(&wps[4 * oq + dd][4 * h2]);
            ((float*)&zv)[dd] = vv0 * wp.x + vv1 * wp.y + vv2 * wp.z + vv3 * wp.w;
        }
        *reinterpret_cast<float4*>(&Zl[k][4 * oq]) = zv;
    }
    __syncthreads();

    // ---- phase C: out[t][4j+d], split over k-halves + shfl combine ----
    {
        int j = h;
        float o0 = 0.f, o1 = 0.f, o2 = 0.f, o3 = 0.f;
#pragma unroll
        for (int k4 = 0; k4 < 4; ++k4) {
            float4 pv = *reinterpret_cast<const float4*>(&pbuf[tl][16 * s + 4 * k4]);
#pragma unroll
            for (int kk = 0; kk < 4; ++kk) {
                float p = ((const float*)&pv)[kk];
                float4 zv = *reinterpret_cast<const float4*>(&Zl[16 * s + 4 * k4 + kk][4 * j]);
                o0 += p * zv.x; o1 += p * zv.y; o2 += p * zv.z; o3 += p * zv.w;
            }
        }
        o0 += __shfl_xor(o0, 1, 64); o1 += __shfl_xor(o1, 1, 64);
        o2 += __shfl_xor(o2, 1, 64); o3 += __shfl_xor(o3, 1, 64);
        if (s == 0) {
            float4 ov;
            ov.x = bps[4 * j + 0] + o0; ov.y = bps[4 * j + 1] + o1;
            ov.z = bps[4 * j + 2] + o2; ov.w = bps[4 * j + 3] + o3;
            float* orow = out + ((size_t)b * TT + t0 + tl) * CE;
            *reinterpret_cast<float4*>(orow + 4 * j) = ov;
        }
    }
}

extern "C" void kernel_launch(void* const* d_in, const int* in_sizes, int n_in,
                              void* d_out, int out_size, void* d_ws, size_t ws_size,
                              hipStream_t stream) {
    const float* x  = (const float*)d_in[0];
    const float* Wq = (const float*)d_in[1];
    const float* bq = (const float*)d_in[2];
    // d_in[3] = Wk, d_in[4] = bk : unused by the reference math
    const float* Wv = (const float*)d_in[5];
    const float* bv = (const float*)d_in[6];
    const float* Wp = (const float*)d_in[7];
    const float* bp = (const float*)d_in[8];
    float* out = (float*)d_out;

    unsigned int* cnt = (unsigned int*)d_ws;              // 4 uints (+pad to 256B)
    float* partial    = (float*)((char*)d_ws + 256);      // [4][128][128] = 256 KiB

    hipMemsetAsync(d_ws, 0, 64, stream);                  // zero flags each call
    hipLaunchKernelGGL(k_fused, dim3(512), dim3(256), 0, stream,
                       x, Wq, bq, Wv, bv, Wp, bp, cnt, partial, out);
}

// Round 6
// 12.386 us; speedup vs baseline: 8.3897x; 8.3897x over previous
//
#include <hip/hip_runtime.h>
#include <math.h>

#define TT 2048
#define CE 32

__device__ __forceinline__ float clip100(float v) {
    return fminf(fmaxf(v, -100.f), 100.f);
}

__device__ __forceinline__ float4 shfl_xor4(float4 v, int m) {
    float4 r;
    r.x = __shfl_xor(v.x, m, 64);
    r.y = __shfl_xor(v.y, m, 64);
    r.z = __shfl_xor(v.z, m, 64);
    r.w = __shfl_xor(v.w, m, 64);
    return r;
}

// ---------------------------------------------------------------------------
// Single fused kernel, NO cross-block communication.
// 256 blocks x 512 threads; block = 32 tokens of batch b (64 blocks/batch).
// tid = tl*16 + h*2 + s (tl token 0..31, h head 0..7, s half).
// Each block redundantly computes xavg[b] (phase-mean of its whole batch) by
// streaming the batch's 256 KB from L2 (x = 1 MB total, L2-resident).
// Then: q GEMV -> in-wave rxtx + softmax -> Z (xavg path) -> out = bp + p@Z.
// All reductions fixed-order -> deterministic. d_ws unused.
// ---------------------------------------------------------------------------
__global__ __launch_bounds__(512, 2) void k_fused(const float* __restrict__ x,
        const float* __restrict__ Wq, const float* __restrict__ bq,
        const float* __restrict__ Wv, const float* __restrict__ bv,
        const float* __restrict__ Wp, const float* __restrict__ bp,
        float* __restrict__ out) {
    int blk = blockIdx.x;
    int b   = blk >> 6;                    // 64 blocks per batch
    int t0  = (blk & 63) * 32;
    int tid = threadIdx.x;                 // 0..511
    int tl  = tid >> 4;                    // 0..31
    int h   = (tid >> 1) & 7;              // 0..7
    int s   = tid & 1;

    __shared__ float xs[32][33];
    __shared__ float wqs[32][33];
    __shared__ float wvs[32][33];
    __shared__ float wps[32][33];
    __shared__ float pbuf[32][36];
    __shared__ float Zl[32][36];
    __shared__ float xavg[4][33];
    __shared__ float4 red4[16][32];
    __shared__ float bqs[32], bvs[32], bps[32];

    // ---- stage: weights (tid<256), x tile + biases (tid>=256) ----
    if (tid < 256) {
        int rr = tid >> 3, cq = tid & 7;
        *reinterpret_cast<float4*>(&wqs[rr][cq * 4]) =
            *reinterpret_cast<const float4*>(Wq + rr * 32 + cq * 4);
        *reinterpret_cast<float4*>(&wvs[rr][cq * 4]) =
            *reinterpret_cast<const float4*>(Wv + rr * 32 + cq * 4);
        *reinterpret_cast<float4*>(&wps[rr][cq * 4]) =
            *reinterpret_cast<const float4*>(Wp + rr * 32 + cq * 4);
    } else {
        int u = tid - 256;
        int r2 = u >> 3, q2 = u & 7;
        *reinterpret_cast<float4*>(&xs[r2][q2 * 4]) =
            *reinterpret_cast<const float4*>(x + ((size_t)b * TT + t0 + r2) * CE + q2 * 4);
        if (u < 32)      bqs[u] = bq[u];
        else if (u < 64) bvs[u - 32] = bv[u - 32];
        else if (u < 96) bps[u - 64] = bp[u - 64];
    }

    // ---- redundant batch phase-sum: x[b] as [512][128] = 16384 float4 ----
    // thread reads f4 = tid + 512*it -> colgroup = tid&31 (fixed), rows rg+16it.
    {
        const float4* xb4 = reinterpret_cast<const float4*>(x + (size_t)b * TT * CE);
        float4 acc; acc.x = 0.f; acc.y = 0.f; acc.z = 0.f; acc.w = 0.f;
#pragma unroll 8
        for (int it = 0; it < 32; ++it) {
            float4 v = xb4[tid + 512 * it];
            acc.x += v.x; acc.y += v.y; acc.z += v.z; acc.w += v.w;
        }
        red4[tid >> 5][tid & 31] = acc;
    }
    __syncthreads();   // s1: staging + red4 complete

    // ---- finalize xavg (tid<128): (c,e) = (tid>>5, tid&31) ----
    if (tid < 128) {
        int c = tid >> 5, e = tid & 31;
        int g = c * 8 + (e >> 2), comp = e & 3;
        float sm = 0.f;
#pragma unroll
        for (int rg = 0; rg < 16; ++rg)
            sm += reinterpret_cast<const float*>(&red4[rg][g])[comp];
        xavg[c][e] = sm * (1.f / 512.f);
    }

    // ---- phase A: q half-dot (e-range s*16..), combine via shfl ----
    float4 myq;
    {
        float a0 = 0.f, a1 = 0.f, a2 = 0.f, a3 = 0.f;
#pragma unroll
        for (int e4 = 0; e4 < 4; ++e4) {
            int e = s * 16 + e4 * 4;
            float4 xv = *reinterpret_cast<const float4*>(&xs[tl][e]);
            float4 w0 = *reinterpret_cast<const float4*>(&wqs[4 * h + 0][e]);
            float4 w1 = *reinterpret_cast<const float4*>(&wqs[4 * h + 1][e]);
            float4 w2 = *reinterpret_cast<const float4*>(&wqs[4 * h + 2][e]);
            float4 w3 = *reinterpret_cast<const float4*>(&wqs[4 * h + 3][e]);
            a0 += xv.x * w0.x + xv.y * w0.y + xv.z * w0.z + xv.w * w0.w;
            a1 += xv.x * w1.x + xv.y * w1.y + xv.z * w1.z + xv.w * w1.w;
            a2 += xv.x * w2.x + xv.y * w2.y + xv.z * w2.z + xv.w * w2.w;
            a3 += xv.x * w3.x + xv.y * w3.y + xv.z * w3.z + xv.w * w3.w;
        }
        myq.x = clip100(bqs[4 * h + 0] + a0 + __shfl_xor(a0, 1, 64));
        myq.y = clip100(bqs[4 * h + 1] + a1 + __shfl_xor(a1, 1, 64));
        myq.z = clip100(bqs[4 * h + 2] + a2 + __shfl_xor(a2, 1, 64));
        myq.w = clip100(bqs[4 * h + 3] + a3 + __shfl_xor(a3, 1, 64));
    }

    // ---- phase B1: in-wave q-block exchange + rxtx + softmax -> pbuf ----
    {
        int r = tl & 3;
        float4 q16 = shfl_xor4(myq, 16);
        float4 q32 = shfl_xor4(myq, 32);
        float4 q48 = shfl_xor4(myq, 48);
        float4 R0 = (r == 0) ? myq : (r == 1) ? q16 : (r == 2) ? q32 : q48;
        float4 R1 = (r == 1) ? myq : (r == 0) ? q16 : (r == 3) ? q32 : q48;
        float4 R2 = (r == 2) ? myq : (r == 3) ? q16 : (r == 0) ? q32 : q48;
        float4 R3 = (r == 3) ? myq : (r == 2) ? q16 : (r == 1) ? q32 : q48;

        float X1 = R0.x, X2 = R0.y, X3 = R0.z, X4 = R0.w;
        float X5 = R1.x, X6 = R1.y, X7 = R1.z, X8 = R1.w;
        float X9 = R2.x, X10 = R2.y, X11 = R2.z, X12 = R2.w;
        float X13 = R3.x, X14 = R3.y, X15 = R3.z, X16 = R3.w;

        float m1  = (-X2 + X3 - X4 + X8) * (X8 + X11);
        float m2  = (X1 - X5 - X6 + X7) * (X15 + X5);
        float m3  = (-X2 + X12) * (-X10 + X16 + X12);
        float m4  = (X9 - X6) * (X13 + X9 - X14);
        float m5  = (X2 + X11) * (-X6 + X15 - X7);
        float m6  = (X6 + X11) * (X6 + X7 - X11);
        float m7  = X11 * (X6 + X7);
        float m8  = X2 * (-X14 - X10 + X6 - X15 + X7 + X16 + X12);
        float m9  = X6 * (X13 + X9 - X14 - X10 + X6 + X7 - X11);
        float m10 = (X2 - X3 + X7 + X11 + X4 - X8) * X11;
        float m11 = (X5 + X6 - X7) * X5;
        float m12 = (X2 - X3 + X4) * X8;
        float m13 = (-X1 + X5 + X6 + X3 - X7 + X11) * X15;
        float m14 = (-X1 + X5 + X6) * (X13 + X9 + X15);
        float m15 = (X2 + X4 - X8) * (X11 + X16 + X12);
        float m16 = (X1 - X8) * (X9 - X16);
        float m17 = X12 * (X10 - X12);
        float m18 = X9 * (X13 - X14);
        float m19 = (-X2 + X3) * (-X15 + X7 + X8);
        float m20 = (X5 + X9 - X8) * X9;
        float m21 = X8 * (X9 - X8 + X12);
        float m22 = (-X6 + X7) * (X5 + X7 - X11);
        float m23 = X1 * (X13 - X5 + X16);
        float m24 = (-X1 + X4 + X12) * X16;
        float m25 = (X9 + X2 + X10) * X14;
        float m26 = (X6 + X10 + X12) * X10;
        float z1 = m7 - m11 - m12;
        float z2 = m1 + m12 + m21;
        float z3 = m3 + m17 - m24;
        float z4 = m2 + m11 + m23;
        float z5 = m5 + m7 + m8;
        float z6 = m4 - m18 - m20;
        float z7 = m6 - m7 - m9;
        float z8 = m17 + m18;
        float c01 = m2 - m5 - z1 + m13 + m19;
        float c02 = z2 + z3 + m15 + m16;
        float c03 = z4 - z3 - z5 - m13;
        float c11 = m1 + m6 - z1 + m10 + m22;
        float c12 = z2 - z6 + z7 + m10;
        float c13 = z4 + z6 + m14 + m16;
        float c22 = m4 - z7 - z8 + m26;
        float c23 = m3 + z5 + z8 + m25;

        float g0, g1, g2, g3;
        if (r == 0)      { g0 = 0.f; g1 = c01; g2 = c02; g3 = c03; }
        else if (r == 1) { g0 = c01; g1 = c11; g2 = c12; g3 = c13; }
        else if (r == 2) { g0 = c02; g1 = c12; g2 = c22; g3 = c23; }
        else             { g0 = c03; g1 = c13; g2 = c23; g3 = 0.f; }
        g0 = clip100(g0) * 0.5f; g1 = clip100(g1) * 0.5f;
        g2 = clip100(g2) * 0.5f; g3 = clip100(g3) * 0.5f;

        float mx = fmaxf(fmaxf(g0, g1), fmaxf(g2, g3));
        float p0 = __expf(g0 - mx), p1 = __expf(g1 - mx);
        float p2 = __expf(g2 - mx), p3 = __expf(g3 - mx);
        float inv = 1.f / (p0 + p1 + p2 + p3);
        if (s == 0) {
            float4 pv; pv.x = p0 * inv; pv.y = p1 * inv;
            pv.z = p2 * inv; pv.w = p3 * inv;
            *reinterpret_cast<float4*>(&pbuf[tl][4 * h]) = pv;
        }
    }
    __syncthreads();   // s2: xavg + pbuf complete

    // ---- phase B2: Z[k][.] ; tasks (k = tid>>4, oq = (tid>>1)&7, sh = tid&1) ----
    {
        int k  = tid >> 4;        // 0..31
        int oq = (tid >> 1) & 7;  // 0..7
        int sh = tid & 1;
        int h2 = k >> 2, c2 = k & 3;
        float vv0 = 0.f, vv1 = 0.f, vv2 = 0.f, vv3 = 0.f;
#pragma unroll
        for (int e4 = 0; e4 < 4; ++e4) {
            int e = sh * 16 + e4 * 4;
            float xa0 = xavg[c2][e + 0];
            float xa1 = xavg[c2][e + 1];
            float xa2 = xavg[c2][e + 2];
            float xa3 = xavg[c2][e + 3];
            float4 w0 = *reinterpret_cast<const float4*>(&wvs[4 * h2 + 0][e]);
            float4 w1 = *reinterpret_cast<const float4*>(&wvs[4 * h2 + 1][e]);
            float4 w2 = *reinterpret_cast<const float4*>(&wvs[4 * h2 + 2][e]);
            float4 w3 = *reinterpret_cast<const float4*>(&wvs[4 * h2 + 3][e]);
            vv0 += xa0 * w0.x + xa1 * w0.y + xa2 * w0.z + xa3 * w0.w;
            vv1 += xa0 * w1.x + xa1 * w1.y + xa2 * w1.z + xa3 * w1.w;
            vv2 += xa0 * w2.x + xa1 * w2.y + xa2 * w2.z + xa3 * w2.w;
            vv3 += xa0 * w3.x + xa1 * w3.y + xa2 * w3.z + xa3 * w3.w;
        }
        vv0 = bvs[4 * h2 + 0] + vv0 + __shfl_xor(vv0, 1, 64);
        vv1 = bvs[4 * h2 + 1] + vv1 + __shfl_xor(vv1, 1, 64);
        vv2 = bvs[4 * h2 + 2] + vv2 + __shfl_xor(vv2, 1, 64);
        vv3 = bvs[4 * h2 + 3] + vv3 + __shfl_xor(vv3, 1, 64);
        float zz[2];
#pragma unroll
        for (int dd2 = 0; dd2 < 2; ++dd2) {
            int dd = 2 * sh + dd2;
            float4 wp = *reinterpret_cast<const float4*>(&wps[4 * oq + dd][4 * h2]);
            zz[dd2] = vv0 * wp.x + vv1 * wp.y + vv2 * wp.z + vv3 * wp.w;
        }
        float2 z2v; z2v.x = zz[0]; z2v.y = zz[1];
        *reinterpret_cast<float2*>(&Zl[k][4 * oq + 2 * sh]) = z2v;
    }
    __syncthreads();   // s3: Zl complete

    // ---- phase C: out[t][4j+d], split over k-halves + shfl combine ----
    {
        int j = h;
        float o0 = 0.f, o1 = 0.f, o2 = 0.f, o3 = 0.f;
#pragma unroll
        for (int k4 = 0; k4 < 4; ++k4) {
            float4 pv = *reinterpret_cast<const float4*>(&pbuf[tl][16 * s + 4 * k4]);
#pragma unroll
            for (int kk = 0; kk < 4; ++kk) {
                float p = ((const float*)&pv)[kk];
                float4 zv = *reinterpret_cast<const float4*>(&Zl[16 * s + 4 * k4 + kk][4 * j]);
                o0 += p * zv.x; o1 += p * zv.y; o2 += p * zv.z; o3 += p * zv.w;
            }
        }
        o0 += __shfl_xor(o0, 1, 64); o1 += __shfl_xor(o1, 1, 64);
        o2 += __shfl_xor(o2, 1, 64); o3 += __shfl_xor(o3, 1, 64);
        if (s == 0) {
            float4 ov;
            ov.x = bps[4 * j + 0] + o0; ov.y = bps[4 * j + 1] + o1;
            ov.z = bps[4 * j + 2] + o2; ov.w = bps[4 * j + 3] + o3;
            float* orow = out + ((size_t)b * TT + t0 + tl) * CE;
            *reinterpret_cast<float4*>(orow + 4 * j) = ov;
        }
    }
}

extern "C" void kernel_launch(void* const* d_in, const int* in_sizes, int n_in,
                              void* d_out, int out_size, void* d_ws, size_t ws_size,
                              hipStream_t stream) {
    const float* x  = (const float*)d_in[0];
    const float* Wq = (const float*)d_in[1];
    const float* bq = (const float*)d_in[2];
    // d_in[3] = Wk, d_in[4] = bk : unused by the reference math
    const float* Wv = (const float*)d_in[5];
    const float* bv = (const float*)d_in[6];
    const float* Wp = (const float*)d_in[7];
    const float* bp = (const float*)d_in[8];
    float* out = (float*)d_out;

    hipLaunchKernelGGL(k_fused, dim3(256), dim3(512), 0, stream,
                       x, Wq, bq, Wv, bv, Wp, bp, out);
}

// Round 7
// 11.655 us; speedup vs baseline: 8.9159x; 1.0627x over previous
//
#include <hip/hip_runtime.h>
#include <math.h>

#define TT 2048
#define CE 32

__device__ __forceinline__ float clip100(float v) {
    return fminf(fmaxf(v, -100.f), 100.f);
}

__device__ __forceinline__ float4 shfl_xor4(float4 v, int m) {
    float4 r;
    r.x = __shfl_xor(v.x, m, 64);
    r.y = __shfl_xor(v.y, m, 64);
    r.z = __shfl_xor(v.z, m, 64);
    r.w = __shfl_xor(v.w, m, 64);
    return r;
}

// ---------------------------------------------------------------------------
// Single fused kernel, wave-specialized producer/consumer INSIDE each block.
// 256 blocks x 512 threads; block = 32 tokens of batch b (64 blocks/batch).
//   X group (tid 0..255):  tid = tl*8 + h. Stage weights; then q GEMV from LDS
//                          + in-wave rxtx + softmax -> pbuf. Pure LDS/VALU.
//   Y group (tid 256..511): stage x-tile + biases; then redundant batch phase-
//                          sum: 64 float4 L2 loads/thread (256 KB/block, x is
//                          L2-resident). Pure VMEM. Overlaps X (m114).
// Then: xavg finalize -> Z build -> out = bp + p@Z. Fixed-order reductions ->
// deterministic. No cross-block communication, d_ws unused.
// ---------------------------------------------------------------------------
__global__ __launch_bounds__(512, 2) void k_fused(const float* __restrict__ x,
        const float* __restrict__ Wq, const float* __restrict__ bq,
        const float* __restrict__ Wv, const float* __restrict__ bv,
        const float* __restrict__ Wp, const float* __restrict__ bp,
        float* __restrict__ out) {
    int blk = blockIdx.x;
    int b   = blk >> 6;                    // 64 blocks per batch
    int t0  = (blk & 63) * 32;
    int tid = threadIdx.x;                 // 0..511

    __shared__ float xs[32][33];
    __shared__ float wqs[32][33];
    __shared__ float wvs[32][33];
    __shared__ float wps[32][33];
    __shared__ float pbuf[32][36];
    __shared__ float Zl[32][36];
    __shared__ float xavg[4][33];
    __shared__ float4 red4[8][32];
    __shared__ float bqs[32], bvs[32], bps[32];

    // ---- stage: X -> weights; Y -> x tile + biases ----
    if (tid < 256) {
        int rr = tid >> 3, cq = tid & 7;
        *reinterpret_cast<float4*>(&wqs[rr][cq * 4]) =
            *reinterpret_cast<const float4*>(Wq + rr * 32 + cq * 4);
        *reinterpret_cast<float4*>(&wvs[rr][cq * 4]) =
            *reinterpret_cast<const float4*>(Wv + rr * 32 + cq * 4);
        *reinterpret_cast<float4*>(&wps[rr][cq * 4]) =
            *reinterpret_cast<const float4*>(Wp + rr * 32 + cq * 4);
    } else {
        int u = tid - 256;
        int r2 = u >> 3, q2 = u & 7;
        *reinterpret_cast<float4*>(&xs[r2][q2 * 4]) =
            *reinterpret_cast<const float4*>(x + ((size_t)b * TT + t0 + r2) * CE + q2 * 4);
        if (u < 32)      bqs[u] = bq[u];
        else if (u < 64) bvs[u - 32] = bv[u - 32];
        else if (u < 96) bps[u - 64] = bp[u - 64];
    }
    __syncthreads();   // s1: LDS staged

    if (tid >= 256) {
        // ---- Y: redundant batch phase-sum, x[b] as [512][128] f32 ----
        // f4 index f = u + 256*it -> colgroup (u&31) fixed, rows (u>>5)+8*it.
        int u = tid - 256;
        const float4* xb4 = reinterpret_cast<const float4*>(x + (size_t)b * TT * CE);
        float4 acc; acc.x = 0.f; acc.y = 0.f; acc.z = 0.f; acc.w = 0.f;
#pragma unroll 16
        for (int it = 0; it < 64; ++it) {
            float4 v = xb4[u + 256 * it];
            acc.x += v.x; acc.y += v.y; acc.z += v.z; acc.w += v.w;
        }
        red4[u >> 5][u & 31] = acc;
    } else {
        // ---- X: phase A (q GEMV) for (tl, h) = (tid>>3, tid&7) ----
        int tl = tid >> 3, h = tid & 7;
        float a0 = bqs[4 * h + 0], a1 = bqs[4 * h + 1];
        float a2 = bqs[4 * h + 2], a3 = bqs[4 * h + 3];
#pragma unroll
        for (int e4 = 0; e4 < 8; ++e4) {
            float4 xv = *reinterpret_cast<const float4*>(&xs[tl][e4 * 4]);
            float4 w0 = *reinterpret_cast<const float4*>(&wqs[4 * h + 0][e4 * 4]);
            float4 w1 = *reinterpret_cast<const float4*>(&wqs[4 * h + 1][e4 * 4]);
            float4 w2 = *reinterpret_cast<const float4*>(&wqs[4 * h + 2][e4 * 4]);
            float4 w3 = *reinterpret_cast<const float4*>(&wqs[4 * h + 3][e4 * 4]);
            a0 += xv.x * w0.x + xv.y * w0.y + xv.z * w0.z + xv.w * w0.w;
            a1 += xv.x * w1.x + xv.y * w1.y + xv.z * w1.z + xv.w * w1.w;
            a2 += xv.x * w2.x + xv.y * w2.y + xv.z * w2.z + xv.w * w2.w;
            a3 += xv.x * w3.x + xv.y * w3.y + xv.z * w3.z + xv.w * w3.w;
        }
        float4 myq;
        myq.x = clip100(a0); myq.y = clip100(a1);
        myq.z = clip100(a2); myq.w = clip100(a3);

        // ---- X: phase B1 — in-wave q-block exchange (masks 8/16/24) ----
        int r = tl & 3;
        float4 q8  = shfl_xor4(myq, 8);    // row r^1
        float4 q16 = shfl_xor4(myq, 16);   // row r^2
        float4 q24 = shfl_xor4(myq, 24);   // row r^3
        float4 R0 = (r == 0) ? myq : (r == 1) ? q8 : (r == 2) ? q16 : q24;
        float4 R1 = (r == 1) ? myq : (r == 0) ? q8 : (r == 3) ? q16 : q24;
        float4 R2 = (r == 2) ? myq : (r == 3) ? q8 : (r == 0) ? q16 : q24;
        float4 R3 = (r == 3) ? myq : (r == 2) ? q8 : (r == 1) ? q16 : q24;

        float X1 = R0.x, X2 = R0.y, X3 = R0.z, X4 = R0.w;
        float X5 = R1.x, X6 = R1.y, X7 = R1.z, X8 = R1.w;
        float X9 = R2.x, X10 = R2.y, X11 = R2.z, X12 = R2.w;
        float X13 = R3.x, X14 = R3.y, X15 = R3.z, X16 = R3.w;

        float m1  = (-X2 + X3 - X4 + X8) * (X8 + X11);
        float m2  = (X1 - X5 - X6 + X7) * (X15 + X5);
        float m3  = (-X2 + X12) * (-X10 + X16 + X12);
        float m4  = (X9 - X6) * (X13 + X9 - X14);
        float m5  = (X2 + X11) * (-X6 + X15 - X7);
        float m6  = (X6 + X11) * (X6 + X7 - X11);
        float m7  = X11 * (X6 + X7);
        float m8  = X2 * (-X14 - X10 + X6 - X15 + X7 + X16 + X12);
        float m9  = X6 * (X13 + X9 - X14 - X10 + X6 + X7 - X11);
        float m10 = (X2 - X3 + X7 + X11 + X4 - X8) * X11;
        float m11 = (X5 + X6 - X7) * X5;
        float m12 = (X2 - X3 + X4) * X8;
        float m13 = (-X1 + X5 + X6 + X3 - X7 + X11) * X15;
        float m14 = (-X1 + X5 + X6) * (X13 + X9 + X15);
        float m15 = (X2 + X4 - X8) * (X11 + X16 + X12);
        float m16 = (X1 - X8) * (X9 - X16);
        float m17 = X12 * (X10 - X12);
        float m18 = X9 * (X13 - X14);
        float m19 = (-X2 + X3) * (-X15 + X7 + X8);
        float m20 = (X5 + X9 - X8) * X9;
        float m21 = X8 * (X9 - X8 + X12);
        float m22 = (-X6 + X7) * (X5 + X7 - X11);
        float m23 = X1 * (X13 - X5 + X16);
        float m24 = (-X1 + X4 + X12) * X16;
        float m25 = (X9 + X2 + X10) * X14;
        float m26 = (X6 + X10 + X12) * X10;
        float z1 = m7 - m11 - m12;
        float z2 = m1 + m12 + m21;
        float z3 = m3 + m17 - m24;
        float z4 = m2 + m11 + m23;
        float z5 = m5 + m7 + m8;
        float z6 = m4 - m18 - m20;
        float z7 = m6 - m7 - m9;
        float z8 = m17 + m18;
        float c01 = m2 - m5 - z1 + m13 + m19;
        float c02 = z2 + z3 + m15 + m16;
        float c03 = z4 - z3 - z5 - m13;
        float c11 = m1 + m6 - z1 + m10 + m22;
        float c12 = z2 - z6 + z7 + m10;
        float c13 = z4 + z6 + m14 + m16;
        float c22 = m4 - z7 - z8 + m26;
        float c23 = m3 + z5 + z8 + m25;

        float g0, g1, g2, g3;
        if (r == 0)      { g0 = 0.f; g1 = c01; g2 = c02; g3 = c03; }
        else if (r == 1) { g0 = c01; g1 = c11; g2 = c12; g3 = c13; }
        else if (r == 2) { g0 = c02; g1 = c12; g2 = c22; g3 = c23; }
        else             { g0 = c03; g1 = c13; g2 = c23; g3 = 0.f; }
        g0 = clip100(g0) * 0.5f; g1 = clip100(g1) * 0.5f;
        g2 = clip100(g2) * 0.5f; g3 = clip100(g3) * 0.5f;

        float mx = fmaxf(fmaxf(g0, g1), fmaxf(g2, g3));
        float p0 = __expf(g0 - mx), p1 = __expf(g1 - mx);
        float p2 = __expf(g2 - mx), p3 = __expf(g3 - mx);
        float inv = 1.f / (p0 + p1 + p2 + p3);
        float4 pv; pv.x = p0 * inv; pv.y = p1 * inv;
        pv.z = p2 * inv; pv.w = p3 * inv;
        *reinterpret_cast<float4*>(&pbuf[tl][4 * h]) = pv;
    }
    __syncthreads();   // s2: red4 + pbuf complete

    // ---- xavg finalize (tid<128): (c,e) = (tid>>5, tid&31) ----
    if (tid < 128) {
        int c = tid >> 5, e = tid & 31;
        int g = c * 8 + (e >> 2), comp = e & 3;
        float sm = 0.f;
#pragma unroll
        for (int rg = 0; rg < 8; ++rg)
            sm += reinterpret_cast<const float*>(&red4[rg][g])[comp];
        xavg[c][e] = sm * (1.f / 512.f);
    }
    __syncthreads();   // s3: xavg ready

    // ---- phase B2 (X only): Z[k][4oq..] (k = tid>>3, oq = tid&7) ----
    if (tid < 256) {
        int k  = tid >> 3;
        int oq = tid & 7;
        int h2 = k >> 2, c2 = k & 3;
        float vv0 = bvs[4 * h2 + 0], vv1 = bvs[4 * h2 + 1];
        float vv2 = bvs[4 * h2 + 2], vv3 = bvs[4 * h2 + 3];
#pragma unroll
        for (int e4 = 0; e4 < 8; ++e4) {
            float xa0 = xavg[c2][e4 * 4 + 0];
            float xa1 = xavg[c2][e4 * 4 + 1];
            float xa2 = xavg[c2][e4 * 4 + 2];
            float xa3 = xavg[c2][e4 * 4 + 3];
            float4 w0 = *reinterpret_cast<const float4*>(&wvs[4 * h2 + 0][e4 * 4]);
            float4 w1 = *reinterpret_cast<const float4*>(&wvs[4 * h2 + 1][e4 * 4]);
            float4 w2 = *reinterpret_cast<const float4*>(&wvs[4 * h2 + 2][e4 * 4]);
            float4 w3 = *reinterpret_cast<const float4*>(&wvs[4 * h2 + 3][e4 * 4]);
            vv0 += xa0 * w0.x + xa1 * w0.y + xa2 * w0.z + xa3 * w0.w;
            vv1 += xa0 * w1.x + xa1 * w1.y + xa2 * w1.z + xa3 * w1.w;
            vv2 += xa0 * w2.x + xa1 * w2.y + xa2 * w2.z + xa3 * w2.w;
            vv3 += xa0 * w3.x + xa1 * w3.y + xa2 * w3.z + xa3 * w3.w;
        }
        float4 zv;
#pragma unroll
        for (int dd = 0; dd < 4; ++dd) {
            float4 wp = *reinterpret_cast<const float4*>(&wps[4 * oq + dd][4 * h2]);
            ((float*)&zv)[dd] = vv0 * wp.x + vv1 * wp.y + vv2 * wp.z + vv3 * wp.w;
        }
        *reinterpret_cast<float4*>(&Zl[k][4 * oq]) = zv;
    }
    __syncthreads();   // s4: Zl complete

    // ---- phase C (X only): out[t][4j+d] for (tl, j) = (tid>>3, tid&7) ----
    if (tid < 256) {
        int tl = tid >> 3, j = tid & 7;
        float o0 = bps[4 * j + 0], o1 = bps[4 * j + 1];
        float o2 = bps[4 * j + 2], o3 = bps[4 * j + 3];
#pragma unroll
        for (int k4 = 0; k4 < 8; ++k4) {
            float4 pv = *reinterpret_cast<const float4*>(&pbuf[tl][4 * k4]);
#pragma unroll
            for (int kk = 0; kk < 4; ++kk) {
                float p = ((const float*)&pv)[kk];
                float4 zv = *reinterpret_cast<const float4*>(&Zl[4 * k4 + kk][4 * j]);
                o0 += p * zv.x; o1 += p * zv.y; o2 += p * zv.z; o3 += p * zv.w;
            }
        }
        float4 ov; ov.x = o0; ov.y = o1; ov.z = o2; ov.w = o3;
        float* orow = out + ((size_t)b * TT + t0 + tl) * CE;
        *reinterpret_cast<float4*>(orow + 4 * j) = ov;
    }
}

extern "C" void kernel_launch(void* const* d_in, const int* in_sizes, int n_in,
                              void* d_out, int out_size, void* d_ws, size_t ws_size,
                              hipStream_t stream) {
    const float* x  = (const float*)d_in[0];
    const float* Wq = (const float*)d_in[1];
    const float* bq = (const float*)d_in[2];
    // d_in[3] = Wk, d_in[4] = bk : unused by the reference math
    const float* Wv = (const float*)d_in[5];
    const float* bv = (const float*)d_in[6];
    const float* Wp = (const float*)d_in[7];
    const float* bp = (const float*)d_in[8];
    float* out = (float*)d_out;

    hipLaunchKernelGGL(k_fused, dim3(256), dim3(512), 0, stream,
                       x, Wq, bq, Wv, bv, Wp, bp, out);
}

// Round 8
// 11.451 us; speedup vs baseline: 9.0753x; 1.0179x over previous
//
#include <hip/hip_runtime.h>
#include <math.h>

#define TT 2048
#define CE 32

__device__ __forceinline__ float clip100(float v) {
    return fminf(fmaxf(v, -100.f), 100.f);
}

__device__ __forceinline__ float4 shfl_xor4(float4 v, int m) {
    float4 r;
    r.x = __shfl_xor(v.x, m, 64);
    r.y = __shfl_xor(v.y, m, 64);
    r.z = __shfl_xor(v.z, m, 64);
    r.w = __shfl_xor(v.w, m, 64);
    return r;
}

// ---------------------------------------------------------------------------
// Single fused kernel, wave-specialized producer/consumer inside each block.
// 256 blocks x 512 threads; block = 32 tokens of batch b (64 blocks/batch).
//   X group (tid 0..255):  stage weights+biases; q GEMV + in-wave rxtx +
//                          softmax -> pbuf (pure LDS/VALU); then xavg finalize.
//   Y group (tid 256..511): stage x-tile; redundant batch phase-sum (256 KB
//                          L2 stream, per-CU BW floor ~1.8us) -> red4.
// Tail (ALL 512 threads): B2 (Z build, e-half split + shfl) -> C (out, k-half
// split + shfl). Fixed-order reductions -> deterministic. d_ws unused.
// ---------------------------------------------------------------------------
__global__ __launch_bounds__(512, 2) void k_fused(const float* __restrict__ x,
        const float* __restrict__ Wq, const float* __restrict__ bq,
        const float* __restrict__ Wv, const float* __restrict__ bv,
        const float* __restrict__ Wp, const float* __restrict__ bp,
        float* __restrict__ out) {
    int blk = blockIdx.x;
    int b   = blk >> 6;                    // 64 blocks per batch
    int t0  = (blk & 63) * 32;
    int tid = threadIdx.x;                 // 0..511

    __shared__ float xs[32][33];
    __shared__ float wqs[32][33];
    __shared__ float wvs[32][33];
    __shared__ float wps[32][33];
    __shared__ float pbuf[32][36];
    __shared__ float Zl[32][36];
    __shared__ float xavg[4][33];
    __shared__ float4 red4[8][32];
    __shared__ float bqs[32], bvs[32], bps[32];

    // ---- stage: X -> weights + biases; Y -> x tile ----
    if (tid < 256) {
        int rr = tid >> 3, cq = tid & 7;
        *reinterpret_cast<float4*>(&wqs[rr][cq * 4]) =
            *reinterpret_cast<const float4*>(Wq + rr * 32 + cq * 4);
        *reinterpret_cast<float4*>(&wvs[rr][cq * 4]) =
            *reinterpret_cast<const float4*>(Wv + rr * 32 + cq * 4);
        *reinterpret_cast<float4*>(&wps[rr][cq * 4]) =
            *reinterpret_cast<const float4*>(Wp + rr * 32 + cq * 4);
        if (tid < 32)       bqs[tid] = bq[tid];
        else if (tid < 64)  bvs[tid - 32] = bv[tid - 32];
        else if (tid < 96)  bps[tid - 64] = bp[tid - 64];
    } else {
        int u = tid - 256;
        int r2 = u >> 3, q2 = u & 7;
        *reinterpret_cast<float4*>(&xs[r2][q2 * 4]) =
            *reinterpret_cast<const float4*>(x + ((size_t)b * TT + t0 + r2) * CE + q2 * 4);
    }
    __syncthreads();   // s1: LDS staged

    if (tid >= 256) {
        // ---- Y: redundant batch phase-sum, x[b] viewed as [512][128] f32 ----
        // f4 index f = u + 256*it; colgroup g=(f&31) fixed per thread; phase
        // c = g>>3, e = (g&7)*4+comp. Rows (f>>5) sweep all 512.
        int u = tid - 256;
        const float4* xb4 = reinterpret_cast<const float4*>(x + (size_t)b * TT * CE);
        float4 acc; acc.x = 0.f; acc.y = 0.f; acc.z = 0.f; acc.w = 0.f;
#pragma unroll 16
        for (int it = 0; it < 64; ++it) {
            float4 v = xb4[u + 256 * it];
            acc.x += v.x; acc.y += v.y; acc.z += v.z; acc.w += v.w;
        }
        red4[u >> 5][u & 31] = acc;
    } else {
        // ---- X: phase A (q GEMV) for (tl, h) = (tid>>3, tid&7) ----
        int tl = tid >> 3, h = tid & 7;
        float a0 = bqs[4 * h + 0], a1 = bqs[4 * h + 1];
        float a2 = bqs[4 * h + 2], a3 = bqs[4 * h + 3];
#pragma unroll
        for (int e4 = 0; e4 < 8; ++e4) {
            float4 xv = *reinterpret_cast<const float4*>(&xs[tl][e4 * 4]);
            float4 w0 = *reinterpret_cast<const float4*>(&wqs[4 * h + 0][e4 * 4]);
            float4 w1 = *reinterpret_cast<const float4*>(&wqs[4 * h + 1][e4 * 4]);
            float4 w2 = *reinterpret_cast<const float4*>(&wqs[4 * h + 2][e4 * 4]);
            float4 w3 = *reinterpret_cast<const float4*>(&wqs[4 * h + 3][e4 * 4]);
            a0 += xv.x * w0.x + xv.y * w0.y + xv.z * w0.z + xv.w * w0.w;
            a1 += xv.x * w1.x + xv.y * w1.y + xv.z * w1.z + xv.w * w1.w;
            a2 += xv.x * w2.x + xv.y * w2.y + xv.z * w2.z + xv.w * w2.w;
            a3 += xv.x * w3.x + xv.y * w3.y + xv.z * w3.z + xv.w * w3.w;
        }
        float4 myq;
        myq.x = clip100(a0); myq.y = clip100(a1);
        myq.z = clip100(a2); myq.w = clip100(a3);

        // ---- X: phase B1 — in-wave q-block exchange (masks 8/16/24) ----
        int r = tl & 3;
        float4 q8  = shfl_xor4(myq, 8);    // row r^1
        float4 q16 = shfl_xor4(myq, 16);   // row r^2
        float4 q24 = shfl_xor4(myq, 24);   // row r^3
        float4 R0 = (r == 0) ? myq : (r == 1) ? q8 : (r == 2) ? q16 : q24;
        float4 R1 = (r == 1) ? myq : (r == 0) ? q8 : (r == 3) ? q16 : q24;
        float4 R2 = (r == 2) ? myq : (r == 3) ? q8 : (r == 0) ? q16 : q24;
        float4 R3 = (r == 3) ? myq : (r == 2) ? q8 : (r == 1) ? q16 : q24;

        float X1 = R0.x, X2 = R0.y, X3 = R0.z, X4 = R0.w;
        float X5 = R1.x, X6 = R1.y, X7 = R1.z, X8 = R1.w;
        float X9 = R2.x, X10 = R2.y, X11 = R2.z, X12 = R2.w;
        float X13 = R3.x, X14 = R3.y, X15 = R3.z, X16 = R3.w;

        float m1  = (-X2 + X3 - X4 + X8) * (X8 + X11);
        float m2  = (X1 - X5 - X6 + X7) * (X15 + X5);
        float m3  = (-X2 + X12) * (-X10 + X16 + X12);
        float m4  = (X9 - X6) * (X13 + X9 - X14);
        float m5  = (X2 + X11) * (-X6 + X15 - X7);
        float m6  = (X6 + X11) * (X6 + X7 - X11);
        float m7  = X11 * (X6 + X7);
        float m8  = X2 * (-X14 - X10 + X6 - X15 + X7 + X16 + X12);
        float m9  = X6 * (X13 + X9 - X14 - X10 + X6 + X7 - X11);
        float m10 = (X2 - X3 + X7 + X11 + X4 - X8) * X11;
        float m11 = (X5 + X6 - X7) * X5;
        float m12 = (X2 - X3 + X4) * X8;
        float m13 = (-X1 + X5 + X6 + X3 - X7 + X11) * X15;
        float m14 = (-X1 + X5 + X6) * (X13 + X9 + X15);
        float m15 = (X2 + X4 - X8) * (X11 + X16 + X12);
        float m16 = (X1 - X8) * (X9 - X16);
        float m17 = X12 * (X10 - X12);
        float m18 = X9 * (X13 - X14);
        float m19 = (-X2 + X3) * (-X15 + X7 + X8);
        float m20 = (X5 + X9 - X8) * X9;
        float m21 = X8 * (X9 - X8 + X12);
        float m22 = (-X6 + X7) * (X5 + X7 - X11);
        float m23 = X1 * (X13 - X5 + X16);
        float m24 = (-X1 + X4 + X12) * X16;
        float m25 = (X9 + X2 + X10) * X14;
        float m26 = (X6 + X10 + X12) * X10;
        float z1 = m7 - m11 - m12;
        float z2 = m1 + m12 + m21;
        float z3 = m3 + m17 - m24;
        float z4 = m2 + m11 + m23;
        float z5 = m5 + m7 + m8;
        float z6 = m4 - m18 - m20;
        float z7 = m6 - m7 - m9;
        float z8 = m17 + m18;
        float c01 = m2 - m5 - z1 + m13 + m19;
        float c02 = z2 + z3 + m15 + m16;
        float c03 = z4 - z3 - z5 - m13;
        float c11 = m1 + m6 - z1 + m10 + m22;
        float c12 = z2 - z6 + z7 + m10;
        float c13 = z4 + z6 + m14 + m16;
        float c22 = m4 - z7 - z8 + m26;
        float c23 = m3 + z5 + z8 + m25;

        float g0, g1, g2, g3;
        if (r == 0)      { g0 = 0.f; g1 = c01; g2 = c02; g3 = c03; }
        else if (r == 1) { g0 = c01; g1 = c11; g2 = c12; g3 = c13; }
        else if (r == 2) { g0 = c02; g1 = c12; g2 = c22; g3 = c23; }
        else             { g0 = c03; g1 = c13; g2 = c23; g3 = 0.f; }
        g0 = clip100(g0) * 0.5f; g1 = clip100(g1) * 0.5f;
        g2 = clip100(g2) * 0.5f; g3 = clip100(g3) * 0.5f;

        float mx = fmaxf(fmaxf(g0, g1), fmaxf(g2, g3));
        float p0 = __expf(g0 - mx), p1 = __expf(g1 - mx);
        float p2 = __expf(g2 - mx), p3 = __expf(g3 - mx);
        float inv = 1.f / (p0 + p1 + p2 + p3);
        float4 pv; pv.x = p0 * inv; pv.y = p1 * inv;
        pv.z = p2 * inv; pv.w = p3 * inv;
        *reinterpret_cast<float4*>(&pbuf[tl][4 * h]) = pv;
    }
    __syncthreads();   // s2: red4 + pbuf complete

    // ---- xavg finalize on X waves (they idle first): (c,e)=(tid>>5,tid&31) ----
    if (tid < 128) {
        int c = tid >> 5, e = tid & 31;
        int g = c * 8 + (e >> 2), comp = e & 3;
        float sm = 0.f;
#pragma unroll
        for (int rg = 0; rg < 8; ++rg)
            sm += reinterpret_cast<const float*>(&red4[rg][g])[comp];
        xavg[c][e] = sm * (1.f / 512.f);
    }
    __syncthreads();   // s3: xavg ready

    // ---- phase B2 (ALL 512): Z[k][.]; (k, oq, sh) = (tid>>4, (tid>>1)&7, tid&1) ----
    {
        int k  = tid >> 4;        // 0..31
        int oq = (tid >> 1) & 7;  // 0..7
        int sh = tid & 1;
        int h2 = k >> 2, c2 = k & 3;
        float vv0 = 0.f, vv1 = 0.f, vv2 = 0.f, vv3 = 0.f;
#pragma unroll
        for (int e4 = 0; e4 < 4; ++e4) {
            int e = sh * 16 + e4 * 4;
            float xa0 = xavg[c2][e + 0];
            float xa1 = xavg[c2][e + 1];
            float xa2 = xavg[c2][e + 2];
            float xa3 = xavg[c2][e + 3];
            float4 w0 = *reinterpret_cast<const float4*>(&wvs[4 * h2 + 0][e]);
            float4 w1 = *reinterpret_cast<const float4*>(&wvs[4 * h2 + 1][e]);
            float4 w2 = *reinterpret_cast<const float4*>(&wvs[4 * h2 + 2][e]);
            float4 w3 = *reinterpret_cast<const float4*>(&wvs[4 * h2 + 3][e]);
            vv0 += xa0 * w0.x + xa1 * w0.y + xa2 * w0.z + xa3 * w0.w;
            vv1 += xa0 * w1.x + xa1 * w1.y + xa2 * w1.z + xa3 * w1.w;
            vv2 += xa0 * w2.x + xa1 * w2.y + xa2 * w2.z + xa3 * w2.w;
            vv3 += xa0 * w3.x + xa1 * w3.y + xa2 * w3.z + xa3 * w3.w;
        }
        vv0 = bvs[4 * h2 + 0] + vv0 + __shfl_xor(vv0, 1, 64);
        vv1 = bvs[4 * h2 + 1] + vv1 + __shfl_xor(vv1, 1, 64);
        vv2 = bvs[4 * h2 + 2] + vv2 + __shfl_xor(vv2, 1, 64);
        vv3 = bvs[4 * h2 + 3] + vv3 + __shfl_xor(vv3, 1, 64);
        float zz[2];
#pragma unroll
        for (int dd2 = 0; dd2 < 2; ++dd2) {
            int dd = 2 * sh + dd2;
            float4 wp = *reinterpret_cast<const float4*>(&wps[4 * oq + dd][4 * h2]);
            zz[dd2] = vv0 * wp.x + vv1 * wp.y + vv2 * wp.z + vv3 * wp.w;
        }
        float2 z2v; z2v.x = zz[0]; z2v.y = zz[1];
        *reinterpret_cast<float2*>(&Zl[k][4 * oq + 2 * sh]) = z2v;
    }
    __syncthreads();   // s4: Zl complete

    // ---- phase C (ALL 512): out[t][4j+d]; (tl, j, s) = (tid>>4, (tid>>1)&7, tid&1) ----
    {
        int tl = tid >> 4, j = (tid >> 1) & 7, s = tid & 1;
        float o0 = 0.f, o1 = 0.f, o2 = 0.f, o3 = 0.f;
#pragma unroll
        for (int k4 = 0; k4 < 4; ++k4) {
            float4 pv = *reinterpret_cast<const float4*>(&pbuf[tl][16 * s + 4 * k4]);
#pragma unroll
            for (int kk = 0; kk < 4; ++kk) {
                float p = ((const float*)&pv)[kk];
                float4 zv = *reinterpret_cast<const float4*>(&Zl[16 * s + 4 * k4 + kk][4 * j]);
                o0 += p * zv.x; o1 += p * zv.y; o2 += p * zv.z; o3 += p * zv.w;
            }
        }
        o0 += __shfl_xor(o0, 1, 64); o1 += __shfl_xor(o1, 1, 64);
        o2 += __shfl_xor(o2, 1, 64); o3 += __shfl_xor(o3, 1, 64);
        if (s == 0) {
            float4 ov;
            ov.x = bps[4 * j + 0] + o0; ov.y = bps[4 * j + 1] + o1;
            ov.z = bps[4 * j + 2] + o2; ov.w = bps[4 * j + 3] + o3;
            float* orow = out + ((size_t)b * TT + t0 + tl) * CE;
            *reinterpret_cast<float4*>(orow + 4 * j) = ov;
        }
    }
}

extern "C" void kernel_launch(void* const* d_in, const int* in_sizes, int n_in,
                              void* d_out, int out_size, void* d_ws, size_t ws_size,
                              hipStream_t stream) {
    const float* x  = (const float*)d_in[0];
    const float* Wq = (const float*)d_in[1];
    const float* bq = (const float*)d_in[2];
    // d_in[3] = Wk, d_in[4] = bk : unused by the reference math
    const float* Wv = (const float*)d_in[5];
    const float* bv = (const float*)d_in[6];
    const float* Wp = (const float*)d_in[7];
    const float* bp = (const float*)d_in[8];
    float* out = (float*)d_out;

    hipLaunchKernelGGL(k_fused, dim3(256), dim3(512), 0, stream,
                       x, Wq, bq, Wv, bv, Wp, bp, out);
}